// Round 13
// baseline (543.773 us; speedup 1.0000x reference)
//
#include <hip/hip_runtime.h>
#include <hip/hip_bf16.h>

// ---------------------------------------------------------------------------
// SupplyChainGNN: 3-layer GCN (PyG GCNConv semantics) + global mean pool.
//   deg[i] = 1 + indeg(i);  dinv = rsqrt(deg)
//   GEMM (bf16 MFMA) folds dinv into its output: h' = dinv[row]*(A@W) (bf16)
//   agg:  out[i] = dinv[i]*( sum_{e: dst=i} h'[src] + h'[i] ) + b  (+ReLU)
// CSR (by dst) rebuilt on-device every call (workspace is re-poisoned).
//
// R2: H stored bf16 + deep gather pipelining (wave-per-node agg).
// R3: GEMMs -> mfma_f32_16x16x32_bf16, W frags in VGPRs, A direct-global.
// R8: dinv folded into GEMM epilogue (no per-edge dinv gather).
// R9: CSR build -> two-level counting sort (bucket=128 dst nodes, FIFO
//     binning, per-bucket L1-hot col scatter). 582 -> 536us.
// R12: (a) DIAGNOSTIC: agg gather pipeline 8->16 deep (agg32 4->8/half).
//      If agg128 67us drops -> latency-bound; flat -> random-HBM roofline.
//      (b) bhist persists per-block histograms; bfill skips its re-histogram
//      pass (saves a 12.8MB edge stream). (c) cvt_k removed: layer-1 mgemm
//      reads f32 x, converts in-register (same RNE values). (d) wt x3 fused.
// ---------------------------------------------------------------------------

typedef unsigned int uint32;
typedef short short8 __attribute__((ext_vector_type(8)));
typedef float f32x4 __attribute__((ext_vector_type(4)));

#define BSH 7                    // bucket shift: 128 nodes/bucket
#define MAXB 1024                // supports M <= 131072
#define BCH 8192                 // edges per binning block

static __device__ __forceinline__ unsigned short f2bf(float f) {
    uint32 u = __float_as_uint(f);
    return (unsigned short)((u + 0x7fffu + ((u >> 16) & 1u)) >> 16);  // RNE
}
static __device__ __forceinline__ float bf2f_lo(uint32 u) {
    return __uint_as_float(u << 16);
}
static __device__ __forceinline__ float bf2f_hi(uint32 u) {
    return __uint_as_float(u & 0xffff0000u);
}

// ---- zero the bucket counters --------------------------------------------
__global__ __launch_bounds__(256) void zcnt_k(int* bcnt) {
    bcnt[blockIdx.x * 256 + threadIdx.x] = 0;
}

// ---- per-bucket edge histogram; persists per-block hist for bfill ---------
__global__ __launch_bounds__(256) void bhist_k(const int* __restrict__ dst, int E,
                                               int* __restrict__ bcnt,
                                               int* __restrict__ blkhist) {
    __shared__ int h[MAXB];
    for (int i = threadIdx.x; i < MAXB; i += 256) h[i] = 0;
    __syncthreads();
    const int base = blockIdx.x * BCH;
    const int end = min(E, base + BCH);
    for (int e = base + (int)threadIdx.x; e < end; e += 256)
        atomicAdd(&h[__builtin_nontemporal_load(&dst[e]) >> BSH], 1);
    __syncthreads();
    int* bh = blkhist + (size_t)blockIdx.x * MAXB;
    for (int i = threadIdx.x; i < MAXB; i += 256) {
        int c = h[i];
        __builtin_nontemporal_store(c, &bh[i]);
        if (c) atomicAdd(&bcnt[i], c);
    }
}

// ---- exclusive scan of bucket counts (1 block, 4 elems/thread) ------------
__global__ __launch_bounds__(256) void bscan_k(const int* __restrict__ bcnt,
                                               int* __restrict__ bstart,
                                               int* __restrict__ bcur, int B) {
    __shared__ int tot[256];
    const int tid = threadIdx.x;
    int v[4];
    int s = 0;
#pragma unroll
    for (int j = 0; j < 4; j++) {
        int idx = tid * 4 + j;
        v[j] = (idx < B) ? bcnt[idx] : 0;
        s += v[j];
    }
    tot[tid] = s;
    __syncthreads();
    for (int o = 1; o < 256; o <<= 1) {
        int t = (tid >= o) ? tot[tid - o] : 0;
        __syncthreads();
        tot[tid] += t;
        __syncthreads();
    }
    int run = tot[tid] - s;  // exclusive
#pragma unroll
    for (int j = 0; j < 4; j++) {
        int idx = tid * 4 + j;
        if (idx < B) {
            bstart[idx] = run;
            bcur[idx] = run;
            run += v[j];
        }
    }
    if (tid == 255) bstart[B] = run;  // total (v[j]=0 past B)
}

// ---- bin edges into bucket-ordered FIFO (packed: src | dlocal<<20) --------
// Uses bhist's persisted per-block histogram (no re-histogram pass).
__global__ __launch_bounds__(256) void bfill_k(const int* __restrict__ src,
                                               const int* __restrict__ dst, int E,
                                               const int* __restrict__ blkhist,
                                               int* __restrict__ bcur,
                                               int* __restrict__ fifo) {
    __shared__ int h[MAXB];
    __shared__ int base[MAXB];
    const int* bh = blkhist + (size_t)blockIdx.x * MAXB;
    for (int i = threadIdx.x; i < MAXB; i += 256) {
        int c = bh[i];
        base[i] = c ? atomicAdd(&bcur[i], c) : 0;
        h[i] = 0;  // local cursor
    }
    __syncthreads();
    const int b0 = blockIdx.x * BCH;
    const int end = min(E, b0 + BCH);
    for (int e = b0 + (int)threadIdx.x; e < end; e += 256) {
        int d = __builtin_nontemporal_load(&dst[e]);
        int s = __builtin_nontemporal_load(&src[e]);
        int b = d >> BSH;
        int off = base[b] + atomicAdd(&h[b], 1);
        fifo[off] = s | ((d & 127) << 20);
    }
}

// ---- per-bucket degree count (LDS histogram, zero global atomics) ---------
__global__ __launch_bounds__(256) void bdeg_k(const int* __restrict__ fifo,
                                              const int* __restrict__ bstart,
                                              int* __restrict__ deg, int M) {
    __shared__ int h[128];
    const int t = threadIdx.x;
    if (t < 128) h[t] = 0;
    __syncthreads();
    const int lo = bstart[blockIdx.x], hi = bstart[blockIdx.x + 1];
    for (int i = lo + t; i < hi; i += 256)
        atomicAdd(&h[fifo[i] >> 20], 1);
    __syncthreads();
    int node = (blockIdx.x << BSH) + t;
    if (t < 128 && node < M) deg[node] = 1 + h[t];  // +1 self loop
}

__global__ __launch_bounds__(256) void mkdinv_k(const int* __restrict__ deg,
                                                float* __restrict__ dinv, int M) {
    int i = blockIdx.x * 256 + threadIdx.x;
    if (i < M) dinv[i] = rsqrtf((float)deg[i]);
}

// ---- block-scan of edge counts (deg-1) to build rowptr --------------------
__global__ __launch_bounds__(256) void scan1_k(const int* __restrict__ deg, int M,
                                               int* __restrict__ blksum) {
    __shared__ int sh[256];
    int i = blockIdx.x * 256 + threadIdx.x;
    int v = (i < M) ? deg[i] - 1 : 0;
    sh[threadIdx.x] = v;
    __syncthreads();
    for (int o = 128; o > 0; o >>= 1) {
        if (threadIdx.x < o) sh[threadIdx.x] += sh[threadIdx.x + o];
        __syncthreads();
    }
    if (threadIdx.x == 0) blksum[blockIdx.x] = sh[0];
}

__global__ __launch_bounds__(512) void scan2_k(int* __restrict__ blksum, int nb) {
    __shared__ int sh[512];
    int tid = threadIdx.x;
    int v = (tid < nb) ? blksum[tid] : 0;
    sh[tid] = v;
    __syncthreads();
    for (int o = 1; o < 512; o <<= 1) {
        int t = (tid >= o) ? sh[tid - o] : 0;
        __syncthreads();
        sh[tid] += t;
        __syncthreads();
    }
    if (tid < nb) blksum[tid] = sh[tid] - v;  // exclusive
}

__global__ __launch_bounds__(256) void scan3_k(const int* __restrict__ deg, int M,
                                               const int* __restrict__ blksum,
                                               int* __restrict__ rowptr,
                                               int* __restrict__ cursor) {
    __shared__ int sh[256];
    int tid = threadIdx.x;
    int i = blockIdx.x * 256 + tid;
    int v = (i < M) ? deg[i] - 1 : 0;
    sh[tid] = v;
    __syncthreads();
    for (int o = 1; o < 256; o <<= 1) {
        int t = (tid >= o) ? sh[tid - o] : 0;
        __syncthreads();
        sh[tid] += t;
        __syncthreads();
    }
    int excl = sh[tid] - v + blksum[blockIdx.x];
    if (i < M) {
        rowptr[i] = excl;
        cursor[i] = excl;
    }
    if (i == M - 1) rowptr[M] = excl + v;
}

// ---- per-bucket CSR col fill: L1-hot 8KB window, full-line merging --------
__global__ __launch_bounds__(256) void bcol_k(const int* __restrict__ fifo,
                                              const int* __restrict__ bstart,
                                              int* __restrict__ cursor,
                                              int* __restrict__ col) {
    const int lo = bstart[blockIdx.x], hi = bstart[blockIdx.x + 1];
    const int nbase = blockIdx.x << BSH;
    for (int i = lo + (int)threadIdx.x; i < hi; i += 256) {
        int ev = fifo[i];
        int node = nbase + (ev >> 20);
        int slot = atomicAdd(&cursor[node], 1);
        col[slot] = ev & 0xFFFFF;
    }
}

// ---- all W transposes in one launch: Wt[N][128] bf16 ----------------------
// rows 0..127 -> Wt1 (from W1, N=128); 128..255 -> Wt2; 256..287 -> Wt3 (N=32)
__global__ __launch_bounds__(256) void wtall_k(const float* __restrict__ W1,
                                               const float* __restrict__ W2,
                                               const float* __restrict__ W3,
                                               unsigned short* __restrict__ Wtall) {
    int idx = blockIdx.x * 256 + threadIdx.x;
    if (idx >= 288 * 128) return;
    int r = idx >> 7, k = idx & 127;
    float v;
    if (r < 128)      v = W1[k * 128 + r];
    else if (r < 256) v = W2[k * 128 + (r - 128)];
    else              v = W3[k * 32 + (r - 256)];
    Wtall[idx] = f2bf(v);
}

// ---- MFMA GEMM: C[M,N](bf16) = dinv[row] * (A[M,128] @ W) -----------------
// W given as Wt[N][128]. frag: lane r=l&15 (row/col), g=l>>4 (k-group);
// A/B elem j of (g,s) <-> k = 32s+8g+j (consistent pairing => exact).
// C/D (m89-verified): col = l&15, row = 4*(l>>4) + reg.
// F32A: read f32 A and convert in-register (layer 1; same RNE as cvt_k did).
template <int NT, bool F32A>  // NT 16-col tiles; N = 16*NT
__global__ __launch_bounds__(256) void mgemm_k(const void* __restrict__ Av,
                                               const unsigned short* __restrict__ Wt,
                                               const float* __restrict__ dinv,
                                               unsigned short* __restrict__ C,
                                               int M, int nstrips) {
    constexpr int N = NT * 16;
    const int lane = threadIdx.x & 63;
    const int wid = threadIdx.x >> 6;
    const int r = lane & 15;
    const int g = lane >> 4;

    short8 wf[NT][4];
#pragma unroll
    for (int t = 0; t < NT; t++)
#pragma unroll
        for (int s = 0; s < 4; s++)
            wf[t][s] = *(const short8*)&Wt[(size_t)(t * 16 + r) * 128 + s * 32 + g * 8];

    const int stride = gridDim.x * 4;
    for (int strip = blockIdx.x * 4 + wid; strip < nstrips; strip += stride) {
        const int R = strip * 16;
        const int ar = min(R + r, M - 1);
        short8 af[4];
#pragma unroll
        for (int s = 0; s < 4; s++) {
            if (F32A) {
                const float* A = (const float*)Av;
                float4 a0 = *(const float4*)&A[(size_t)ar * 128 + s * 32 + g * 8];
                float4 a1 = *(const float4*)&A[(size_t)ar * 128 + s * 32 + g * 8 + 4];
                short8 v;
                v[0] = (short)f2bf(a0.x); v[1] = (short)f2bf(a0.y);
                v[2] = (short)f2bf(a0.z); v[3] = (short)f2bf(a0.w);
                v[4] = (short)f2bf(a1.x); v[5] = (short)f2bf(a1.y);
                v[6] = (short)f2bf(a1.z); v[7] = (short)f2bf(a1.w);
                af[s] = v;
            } else {
                const unsigned short* A = (const unsigned short*)Av;
                af[s] = *(const short8*)&A[(size_t)ar * 128 + s * 32 + g * 8];
            }
        }
        f32x4 acc[NT];
#pragma unroll
        for (int t = 0; t < NT; t++) acc[t] = (f32x4){0.f, 0.f, 0.f, 0.f};
#pragma unroll
        for (int s = 0; s < 4; s++)
#pragma unroll
            for (int t = 0; t < NT; t++)
                acc[t] = __builtin_amdgcn_mfma_f32_16x16x32_bf16(
                    af[s], wf[t][s], acc[t], 0, 0, 0);
#pragma unroll
        for (int j = 0; j < 4; j++) {
            int row = R + 4 * g + j;
            if (row < M) {
                float dv = dinv[row];
#pragma unroll
                for (int t = 0; t < NT; t++)
                    C[(size_t)row * N + t * 16 + r] = f2bf(dv * acc[t][j]);
            }
        }
    }
}

// ---- aggregation, F=128 (bf16 h' row-major): wave/node, 16-deep gathers ---
__global__ __launch_bounds__(256) void agg128_k(const unsigned short* __restrict__ Hb,
                                                const int* __restrict__ rowptr,
                                                const int* __restrict__ col,
                                                const float* __restrict__ dinv,
                                                const float* __restrict__ bias,
                                                unsigned short* __restrict__ outb,
                                                int M, int relu) {
    int node = blockIdx.x * 4 + (threadIdx.x >> 6);
    if (node >= M) return;
    int lane = threadIdx.x & 63;
    const uint32* Hu = (const uint32*)Hb;  // row = 64 uints (128 bf16)
    uint32 su = Hu[(size_t)node * 64 + lane];
    float ax = bf2f_lo(su);   // self term (h' includes dinv factor)
    float ay = bf2f_hi(su);
    const int s = rowptr[node], e = rowptr[node + 1];

    for (int base = s; base < e; base += 64) {
        int n = e - base;
        if (n > 64) n = 64;
        int cid = __builtin_nontemporal_load(&col[base + (lane < n ? lane : 0)]);
        int j = 0;
        for (; j + 16 <= n; j += 16) {
            int sj[16]; uint32 u[16];
#pragma unroll
            for (int k = 0; k < 16; k++) sj[k] = __shfl(cid, j + k);
#pragma unroll
            for (int k = 0; k < 16; k++) u[k] = Hu[(size_t)sj[k] * 64 + lane];
#pragma unroll
            for (int k = 0; k < 16; k++) {
                ax += bf2f_lo(u[k]);
                ay += bf2f_hi(u[k]);
            }
        }
        for (; j + 8 <= n; j += 8) {
            int sj[8]; uint32 u[8];
#pragma unroll
            for (int k = 0; k < 8; k++) sj[k] = __shfl(cid, j + k);
#pragma unroll
            for (int k = 0; k < 8; k++) u[k] = Hu[(size_t)sj[k] * 64 + lane];
#pragma unroll
            for (int k = 0; k < 8; k++) {
                ax += bf2f_lo(u[k]);
                ay += bf2f_hi(u[k]);
            }
        }
        for (; j < n; j++) {
            int s0 = __shfl(cid, j);
            uint32 u0 = Hu[(size_t)s0 * 64 + lane];
            ax += bf2f_lo(u0);
            ay += bf2f_hi(u0);
        }
    }
    float dv = dinv[node];
    float2 bv = *(const float2*)&bias[lane * 2];
    float ox = fmaf(dv, ax, bv.x), oy = fmaf(dv, ay, bv.y);
    if (relu) { ox = fmaxf(ox, 0.f); oy = fmaxf(oy, 0.f); }
    uint32 pk = (uint32)f2bf(ox) | ((uint32)f2bf(oy) << 16);
    *(uint32*)&outb[(size_t)node * 128 + lane * 2] = pk;
}

// ---- aggregation, F=32 (h' bf16 row-major [M,32]) -> f32 out, 8-deep ------
__global__ __launch_bounds__(256) void agg32_k(const unsigned short* __restrict__ Hb,
                                               const int* __restrict__ rowptr,
                                               const int* __restrict__ col,
                                               const float* __restrict__ dinv,
                                               const float* __restrict__ bias,
                                               float* __restrict__ out, int M) {
    int node = blockIdx.x * 4 + (threadIdx.x >> 6);
    if (node >= M) return;
    int lane = threadIdx.x & 63;
    int f = lane & 31;
    int half = lane >> 5;
    float acc = 0.f;
    if (!half)
        acc = __uint_as_float(((uint32)Hb[(size_t)node * 32 + f]) << 16);  // self
    const int s = rowptr[node], e = rowptr[node + 1];
    int i = s + half;
    for (; i + 14 < e; i += 16) {
        int sj[8];
#pragma unroll
        for (int k = 0; k < 8; k++)
            sj[k] = __builtin_nontemporal_load(&col[i + 2 * k]);
        float hv[8];
#pragma unroll
        for (int k = 0; k < 8; k++)
            hv[k] = __uint_as_float(((uint32)Hb[(size_t)sj[k] * 32 + f]) << 16);
#pragma unroll
        for (int k = 0; k < 8; k++) acc += hv[k];
    }
    for (; i < e; i += 2) {
        int s0 = __builtin_nontemporal_load(&col[i]);
        acc += __uint_as_float(((uint32)Hb[(size_t)s0 * 32 + f]) << 16);
    }
    acc += __shfl_xor(acc, 32);
    if (!half) out[(size_t)node * 32 + f] = fmaf(dinv[node], acc, bias[f]);
}

// ---- global mean pool over sorted batch ids -------------------------------
__global__ __launch_bounds__(256) void pool_k(const float* __restrict__ h,
                                              const int* __restrict__ batch, int M,
                                              float* __restrict__ out) {
    int g = blockIdx.x;
    int lo, hi;
    {
        int l = 0, r = M;
        while (l < r) { int m = (l + r) >> 1; if (batch[m] < g) l = m + 1; else r = m; }
        lo = l;
    }
    {
        int l = lo, r = M;
        while (l < r) { int m = (l + r) >> 1; if (batch[m] < g + 1) l = m + 1; else r = m; }
        hi = l;
    }
    int f = threadIdx.x & 31;
    int chunk = threadIdx.x >> 5;  // 8 chunks
    float acc = 0.f;
    for (int i = lo + chunk; i < hi; i += 8) acc += h[(size_t)i * 32 + f];
    __shared__ float red[8][32];
    red[chunk][f] = acc;
    __syncthreads();
    if (threadIdx.x < 32) {
        float s = 0.f;
#pragma unroll
        for (int c = 0; c < 8; c++) s += red[c][f];
        out[g * 32 + f] = s / fmaxf((float)(hi - lo), 1.f);
    }
}

extern "C" void kernel_launch(void* const* d_in, const int* in_sizes, int n_in,
                              void* d_out, int out_size, void* d_ws, size_t ws_size,
                              hipStream_t stream) {
    const float* x   = (const float*)d_in[0];
    const int* ei    = (const int*)d_in[1];
    const int* batch = (const int*)d_in[2];
    const float* W1  = (const float*)d_in[4];
    const float* b1  = (const float*)d_in[5];
    const float* W2  = (const float*)d_in[6];
    const float* b2  = (const float*)d_in[7];
    const float* W3  = (const float*)d_in[8];
    const float* b3  = (const float*)d_in[9];

    const int M = in_sizes[0] / 128;
    const int E = in_sizes[1] / 2;
    const int G = 64;  // N_GRAPHS (problem constant)
    const int* srcp = ei;
    const int* dstp = ei + E;
    const int B = (M + 127) >> BSH;  // buckets of 128 nodes (B <= MAXB)
    const int nbE = (E + BCH - 1) / BCH;

    // workspace carve (256B aligned)
    char* p = (char*)d_ws;
    auto carve = [&](size_t bytes) {
        void* r = (void*)p;
        p += (bytes + 255) & ~(size_t)255;
        return r;
    };
    int*   deg     = (int*)carve((size_t)M * 4);
    float* dinv    = (float*)carve((size_t)M * 4);
    int*   rowptr  = (int*)carve((size_t)(M + 1) * 4);
    int*   cursor  = (int*)carve((size_t)M * 4);
    int*   blksum  = (int*)carve(512 * 4);
    int*   bcnt    = (int*)carve(MAXB * 4);
    int*   bstart  = (int*)carve((MAXB + 1) * 4);
    int*   bcur    = (int*)carve(MAXB * 4);
    int*   blkhist = (int*)carve((size_t)nbE * MAXB * 4);
    int*   fifo    = (int*)carve((size_t)E * 4);
    int*   col     = (int*)carve((size_t)E * 4);
    unsigned short* Hb    = (unsigned short*)carve((size_t)M * 128 * 2);
    unsigned short* Ob    = (unsigned short*)carve((size_t)M * 128 * 2);
    unsigned short* H3    = (unsigned short*)carve((size_t)M * 32 * 2);
    unsigned short* Wtall = (unsigned short*)carve(288 * 128 * 2);
    unsigned short* Wt1 = Wtall;
    unsigned short* Wt2 = Wtall + 128 * 128;
    unsigned short* Wt3 = Wtall + 256 * 128;

    float* outh = (float*)d_out;             // [M,32]
    float* outg = outh + (size_t)M * 32;     // [G,32]

    const int nbM = (M + 255) / 256;
    const int nstrips = (M + 15) / 16;
    const int gblk = (nstrips + 7) / 8;      // 4 waves/block, ~2 strips/wave

    // --- CSR build: two-level counting sort ---
    zcnt_k<<<MAXB / 256, 256, 0, stream>>>(bcnt);
    bhist_k<<<nbE, 256, 0, stream>>>(dstp, E, bcnt, blkhist);
    bscan_k<<<1, 256, 0, stream>>>(bcnt, bstart, bcur, B);
    bfill_k<<<nbE, 256, 0, stream>>>(srcp, dstp, E, blkhist, bcur, fifo);
    bdeg_k<<<B, 256, 0, stream>>>(fifo, bstart, deg, M);
    mkdinv_k<<<nbM, 256, 0, stream>>>(deg, dinv, M);
    scan1_k<<<nbM, 256, 0, stream>>>(deg, M, blksum);
    scan2_k<<<1, 512, 0, stream>>>(blksum, nbM);
    scan3_k<<<nbM, 256, 0, stream>>>(deg, M, blksum, rowptr, cursor);
    bcol_k<<<B, 256, 0, stream>>>(fifo, bstart, cursor, col);
    // --- weights ---
    wtall_k<<<(288 * 128 + 255) / 256, 256, 0, stream>>>(W1, W2, W3, Wtall);

    // layer 1 (f32 A read direct, converted in-register)
    mgemm_k<8, true><<<gblk, 256, 0, stream>>>(x, Wt1, dinv, Hb, M, nstrips);
    agg128_k<<<(M + 3) / 4, 256, 0, stream>>>(Hb, rowptr, col, dinv, b1, Ob, M, 1);
    // layer 2
    mgemm_k<8, false><<<gblk, 256, 0, stream>>>(Ob, Wt2, dinv, Hb, M, nstrips);
    agg128_k<<<(M + 3) / 4, 256, 0, stream>>>(Hb, rowptr, col, dinv, b2, Ob, M, 1);
    // layer 3
    mgemm_k<2, false><<<gblk, 256, 0, stream>>>(Ob, Wt3, dinv, H3, M, nstrips);
    agg32_k<<<(M + 3) / 4, 256, 0, stream>>>(H3, rowptr, col, dinv, b3, outh, M);
    // pool
    pool_k<<<G, 256, 0, stream>>>(outh, batch, M, outg);
}